// Round 10
// baseline (671.230 us; speedup 1.0000x reference)
//
#include <hip/hip_runtime.h>
#include <hip/hip_bf16.h>
#include <stdint.h>

#define R_TOT   131072
#define D_IN    1024
#define N_CLS   81
#define N_BOX   320
#define N_H     256
#define N1_USED 657
#define N1_PAD  672
#define NB_COLS 336   // per-block N (half of 672)

typedef __attribute__((ext_vector_type(8))) short short8;
typedef __attribute__((ext_vector_type(4))) float f32x4;

__device__ __forceinline__ unsigned short f2bf(float f) {
  union { float f; unsigned u; } v; v.f = f;
  unsigned r = v.u + 0x7FFFu + ((v.u >> 16) & 1u);
  return (unsigned short)(r >> 16);
}

__device__ __forceinline__ short8 cvt8(float4 a, float4 b) {
  short8 v;
  v[0] = (short)f2bf(a.x); v[1] = (short)f2bf(a.y);
  v[2] = (short)f2bf(a.z); v[3] = (short)f2bf(a.w);
  v[4] = (short)f2bf(b.x); v[5] = (short)f2bf(b.y);
  v[6] = (short)f2bf(b.z); v[7] = (short)f2bf(b.w);
  return v;
}

__device__ __forceinline__ void async_lds16(void* lds, const void* g) {
  __builtin_amdgcn_global_load_lds(
      (const __attribute__((address_space(1))) unsigned int*)g,
      (__attribute__((address_space(3))) unsigned int*)lds, 16, 0, 0);
}

// ---------------- prep: pack W_big into K-panels [32][672][32] bf16 ----------------
__global__ void prep_w1(const float* __restrict__ Wc, const float* __restrict__ Wb,
                        const float* __restrict__ W1, unsigned short* __restrict__ Wp)
{
  int idx = blockIdx.x * 256 + threadIdx.x;      // < 672*1024
  int p   = idx / (N1_PAD * 32);
  int rem = idx % (N1_PAD * 32);
  int n   = rem >> 5;
  int kk  = rem & 31;
  int k   = p * 32 + kk;
  float w = 0.f;
  if (n < N_CLS)               w = Wc[(size_t)n * D_IN + k];
  else if (n < N_CLS + N_BOX)  w = Wb[(size_t)(n - N_CLS) * D_IN + k];
  else if (n < N1_USED)        w = W1[(size_t)(n - (N_CLS + N_BOX)) * D_IN + k];
  Wp[idx] = f2bf(w);
}

__global__ void prep_w23(const float* __restrict__ W2, const float* __restrict__ W3,
                         unsigned short* __restrict__ W2b, unsigned short* __restrict__ W3b)
{
  int idx = blockIdx.x * 256 + threadIdx.x;      // < 131072
  if (idx < 65536) W2b[idx] = f2bf(W2[idx]);
  else             W3b[idx - 65536] = f2bf(W3[idx - 65536]);
}

// ---------------- GEMM1: 64(M) x 336(N) per block, K=1024 ----------------
// Grid 4096 = 2048 M-tiles x 2 N-halves; XCD-chunk swizzle for L2/L3 reuse of x.
// 448 threads (7 waves), wave wc owns cols [wc*48,+48). LDS 51.2 KB -> ~3 blocks/CU.
// A-path uses DEPTH-2 register prefetch: at step kp, issue A(kp+2) into one
// named reg pair, ds_write A(kp+1) from the other (issued 1.5 steps earlier,
// ~1500 cyc of cover for the ~900 cyc HBM latency). Named regs + static even/odd
// bodies keep everything in registers (no scratch).
__global__ __launch_bounds__(448, 6) void g1_kernel(
    const float* __restrict__ x, const unsigned short* __restrict__ Wp,
    const float* __restrict__ b_cls, const float* __restrict__ b_box,
    const float* __restrict__ b1,
    float* __restrict__ scores, float* __restrict__ deltas,
    unsigned short* __restrict__ h1)
{
  __shared__ __attribute__((aligned(16))) unsigned short As[2][64 * 32];       // 8 KB
  __shared__ __attribute__((aligned(16))) unsigned short Bs[2][NB_COLS * 32];  // 43 KB

  const int tid  = threadIdx.x;
  const int wave = tid >> 6;
  const int lane = tid & 63;
  // bijective XCD-chunk swizzle (nwg = 4096, 4096 % 8 == 0)
  const int orig  = blockIdx.x;
  const int work  = (orig & 7) * 512 + (orig >> 3);
  const int m0    = (work >> 1) * 64;
  const int nbase = (work & 1) * NB_COLS;

  const int arow = tid >> 2;          // A-staging row (tid < 256)
  const int akq  = tid & 3;           // A-staging k-quad

  f32x4 acc[4][3];
#pragma unroll
  for (int i = 0; i < 4; ++i)
#pragma unroll
    for (int j = 0; j < 3; ++j)
      acc[i][j] = (f32x4){0.f, 0.f, 0.f, 0.f};

  float4 regA0, regA1, regB0, regB1;  // two named A-prefetch buffers

  // ---- prologue: B(0) -> Bs[0]; A(0) -> As[0]; A(1) -> regB ----
  {
    const unsigned short* wsrc = Wp + (size_t)nbase * 32;
#pragma unroll
    for (int i = 0; i < 3; ++i) {
      int chunk = tid + i * 448;                 // 0..1343
      async_lds16((char*)&Bs[0][0] + chunk * 16, (const char*)wsrc + chunk * 16);
    }
    if (tid < 256) {
      const float* src0 = x + (size_t)(m0 + arow) * D_IN + akq * 8;
      float4 f0 = *(const float4*)src0;
      float4 f1 = *(const float4*)(src0 + 4);
      const float* src1 = src0 + 32;             // k-step 1
      regB0 = *(const float4*)src1;
      regB1 = *(const float4*)(src1 + 4);
      *(short8*)&As[0][arow * 32 + akq * 8] = cvt8(f0, f1);
    }
  }
  __syncthreads();

  const int lr = lane & 15;
  const int lk = (lane >> 4) * 8;

  // One K-step: issue A(kp+2)->RISS, stage B(kp+1), compute Bs/As[CUR],
  // write A(kp+1) from RWR, barrier. CUR is a compile-time 0/1.
#define G1_STEP(KP, CUR, RISS0, RISS1, RWR0, RWR1)                              \
  {                                                                             \
    const int kp_ = (KP);                                                       \
    if (kp_ + 2 < 32 && tid < 256) {                                            \
      const float* srcA = x + (size_t)(m0 + arow) * D_IN                        \
                            + (size_t)(kp_ + 2) * 32 + akq * 8;                 \
      RISS0 = *(const float4*)srcA;                                             \
      RISS1 = *(const float4*)(srcA + 4);                                       \
    }                                                                           \
    if (kp_ + 1 < 32) {                                                         \
      const unsigned short* wsrc = Wp + (size_t)(kp_ + 1) * (N1_PAD * 32)       \
                                      + (size_t)nbase * 32;                     \
      _Pragma("unroll")                                                         \
      for (int i = 0; i < 3; ++i) {                                             \
        int chunk = tid + i * 448;                                              \
        async_lds16((char*)&Bs[(CUR) ^ 1][0] + chunk * 16,                      \
                    (const char*)wsrc + chunk * 16);                            \
      }                                                                         \
    }                                                                           \
    short8 af[4], bfr[3];                                                       \
    _Pragma("unroll")                                                           \
    for (int mi = 0; mi < 4; ++mi)                                              \
      af[mi] = *(const short8*)&As[(CUR)][(mi * 16 + lr) * 32 + lk];            \
    _Pragma("unroll")                                                           \
    for (int ni = 0; ni < 3; ++ni)                                              \
      bfr[ni] = *(const short8*)&Bs[(CUR)][(wave * 48 + ni * 16 + lr) * 32 + lk]; \
    _Pragma("unroll")                                                           \
    for (int mi = 0; mi < 4; ++mi)                                              \
      _Pragma("unroll")                                                         \
      for (int ni = 0; ni < 3; ++ni)                                            \
        acc[mi][ni] = __builtin_amdgcn_mfma_f32_16x16x32_bf16(                  \
            af[mi], bfr[ni], acc[mi][ni], 0, 0, 0);                             \
    if (kp_ + 1 < 32 && tid < 256)                                              \
      *(short8*)&As[(CUR) ^ 1][arow * 32 + akq * 8] = cvt8(RWR0, RWR1);         \
    __syncthreads();                                                            \
  }

  for (int kp2 = 0; kp2 < 32; kp2 += 2) {
    G1_STEP(kp2,     0, regA0, regA1, regB0, regB1);   // even: issue->regA, write regB
    G1_STEP(kp2 + 1, 1, regB0, regB1, regA0, regA1);   // odd:  issue->regB, write regA
  }
#undef G1_STEP

  // ---- epilogue: split cols into scores / deltas / h1 ----
  const int rbase = m0 + ((lane >> 4) << 2);
#pragma unroll
  for (int mi = 0; mi < 4; ++mi) {
#pragma unroll
    for (int ni = 0; ni < 3; ++ni) {
      int n = nbase + wave * 48 + ni * 16 + lr;
      if (n >= N1_USED) continue;
      if (n < N_CLS) {
        float bb = b_cls[n];
#pragma unroll
        for (int j = 0; j < 4; ++j) {
          int r = rbase + mi * 16 + j;
          scores[(size_t)r * N_CLS + n] = acc[mi][ni][j] + bb;
        }
      } else if (n < N_CLS + N_BOX) {
        int nb = n - N_CLS;
        float bb = b_box[nb];
#pragma unroll
        for (int j = 0; j < 4; ++j) {
          int r = rbase + mi * 16 + j;
          deltas[(size_t)r * N_BOX + nb] = acc[mi][ni][j] + bb;
        }
      } else {
        int nh = n - (N_CLS + N_BOX);
        float bb = b1[nh];
#pragma unroll
        for (int j = 0; j < 4; ++j) {
          int r = rbase + mi * 16 + j;
          float h = acc[mi][ni][j] + bb;
          h1[(size_t)r * N_H + nh] = f2bf(fmaxf(h, 0.f));
        }
      }
    }
  }
}

// ---------------- GEMM2/3: full-row blocks, 128(M) x 256(N=all), K=256, BK=32 ----
// 512 threads (8 waves), wave (wm,wn) = (wave>>2, wave&3), per-wave 64x64 output.
// Each block reads ONLY A rows [m0,m0+128) and writes ONLY those rows ->
// in-place (out==A) is block-local and race-free. Grid is (R/128, 1).
__device__ __forceinline__ void g23_stage(unsigned short* Asb, unsigned short* Bsb,
    const unsigned short* __restrict__ A, const unsigned short* __restrict__ Bw,
    int m0, int kp, int tid)
{
  {
    int row = tid >> 2, kq = tid & 3;             // A: 512 chunks of 16B
    async_lds16((char*)Asb + tid * 16,
                (const char*)(A + (size_t)(m0 + row) * N_H + (size_t)kp * 32 + kq * 8));
  }
#pragma unroll
  for (int i = 0; i < 2; ++i) {                   // B: 1024 chunks of 16B
    int chunk = tid + i * 512;
    int row = chunk >> 2, kq = chunk & 3;
    async_lds16((char*)Bsb + chunk * 16,
                (const char*)(Bw + (size_t)row * N_H + (size_t)kp * 32 + kq * 8));
  }
}

template <int RELU, int OUT_BF16>
__global__ __launch_bounds__(512, 1) void g23_kernel(
    const unsigned short* __restrict__ A, const unsigned short* __restrict__ Bw,
    const float* __restrict__ bias, void* __restrict__ outv)
{
  __shared__ __attribute__((aligned(16))) unsigned short As[2][128 * 32];
  __shared__ __attribute__((aligned(16))) unsigned short Bs[2][256 * 32];
  const int tid  = threadIdx.x;
  const int wave = tid >> 6, lane = tid & 63;
  const int wm = wave >> 2, wn = wave & 3;
  const int m0 = blockIdx.x * 128;

  f32x4 acc[4][4];
#pragma unroll
  for (int i = 0; i < 4; ++i)
#pragma unroll
    for (int j = 0; j < 4; ++j)
      acc[i][j] = (f32x4){0.f, 0.f, 0.f, 0.f};

  g23_stage(&As[0][0], &Bs[0][0], A, Bw, m0, 0, tid);
  __syncthreads();

  const int lr = lane & 15;
  const int lk = (lane >> 4) * 8;

  for (int kp = 0; kp < 8; ++kp) {
    const int cur = kp & 1, nxt = cur ^ 1;
    if (kp < 7) g23_stage(&As[nxt][0], &Bs[nxt][0], A, Bw, m0, kp + 1, tid);

    short8 af[4], bfr[4];
#pragma unroll
    for (int mi = 0; mi < 4; ++mi)
      af[mi] = *(const short8*)&As[cur][(wm * 64 + mi * 16 + lr) * 32 + lk];
#pragma unroll
    for (int ni = 0; ni < 4; ++ni)
      bfr[ni] = *(const short8*)&Bs[cur][(wn * 64 + ni * 16 + lr) * 32 + lk];
#pragma unroll
    for (int mi = 0; mi < 4; ++mi)
#pragma unroll
      for (int ni = 0; ni < 4; ++ni)
        acc[mi][ni] = __builtin_amdgcn_mfma_f32_16x16x32_bf16(af[mi], bfr[ni], acc[mi][ni], 0, 0, 0);
    __syncthreads();
  }

  // All LDS reads of A done; safe to overwrite our own rows (even if out==A).
#pragma unroll
  for (int mi = 0; mi < 4; ++mi) {
#pragma unroll
    for (int ni = 0; ni < 4; ++ni) {
      int n = wn * 64 + ni * 16 + lr;
      float bb = bias[n];
#pragma unroll
      for (int j = 0; j < 4; ++j) {
        int r = m0 + wm * 64 + mi * 16 + ((lane >> 4) << 2) + j;
        float v = acc[mi][ni][j] + bb;
        if (RELU) v = fmaxf(v, 0.f);
        if (OUT_BF16) ((unsigned short*)outv)[(size_t)r * N_H + n] = f2bf(v);
        else          ((float*)outv)[(size_t)r * N_H + n] = v;
      }
    }
  }
}

// ---------------- launch ----------------
extern "C" void kernel_launch(void* const* d_in, const int* in_sizes, int n_in,
                              void* d_out, int out_size, void* d_ws, size_t ws_size,
                              hipStream_t stream)
{
  const float* x     = (const float*)d_in[0];
  const float* W_cls = (const float*)d_in[1];
  const float* b_cls = (const float*)d_in[2];
  const float* W_box = (const float*)d_in[3];
  const float* b_box = (const float*)d_in[4];
  const float* W1    = (const float*)d_in[5];
  const float* b1    = (const float*)d_in[6];
  const float* W2    = (const float*)d_in[7];
  const float* b2    = (const float*)d_in[8];
  const float* W3    = (const float*)d_in[9];
  const float* b3    = (const float*)d_in[10];

  float* scores = (float*)d_out;
  float* deltas = scores + (size_t)R_TOT * N_CLS;
  float* embeds = deltas + (size_t)R_TOT * N_BOX;

  // Scratch layout (total ~65.6 MB):
  //   Wp  : 672*1024 bf16      = 1,376,256 B
  //   W2b :  65536 bf16        =   131,072 B
  //   W3b :  65536 bf16        =   131,072 B
  //   h   : 131072*256 bf16    = 67,108,864 B  (h1; GEMM2 overwrites in place -> h2)
  char* ws = (char*)d_ws;
  unsigned short* Wp  = (unsigned short*)ws;
  unsigned short* W2b = (unsigned short*)(ws + 1376256);
  unsigned short* W3b = (unsigned short*)(ws + 1376256 + 131072);
  unsigned short* h   = (unsigned short*)(ws + 1638400);

  hipLaunchKernelGGL(prep_w1, dim3(2688), dim3(256), 0, stream, W_cls, W_box, W1, Wp);
  hipLaunchKernelGGL(prep_w23, dim3(512), dim3(256), 0, stream, W2, W3, W2b, W3b);
  hipLaunchKernelGGL(g1_kernel, dim3(4096), dim3(448), 0, stream,
                     x, Wp, b_cls, b_box, b1, scores, deltas, h);
  hipLaunchKernelGGL((g23_kernel<1, 1>), dim3(R_TOT / 128), dim3(512), 0, stream,
                     h, W2b, b2, (void*)h);       // in place: h1 -> h2 (block-local rows)
  hipLaunchKernelGGL((g23_kernel<0, 0>), dim3(R_TOT / 128), dim3(512), 0, stream,
                     h, W3b, b3, (void*)embeds);
}

// Round 11
// 526.991 us; speedup vs baseline: 1.2737x; 1.2737x over previous
//
#include <hip/hip_runtime.h>
#include <hip/hip_bf16.h>
#include <stdint.h>

#define R_TOT   131072
#define D_IN    1024
#define N_CLS   81
#define N_BOX   320
#define N_H     256
#define N1_USED 657
#define N1_PAD  672
#define NB_COLS 336   // per-block N (half of 672)

typedef __attribute__((ext_vector_type(8))) short short8;
typedef __attribute__((ext_vector_type(4))) float f32x4;

__device__ __forceinline__ unsigned short f2bf(float f) {
  union { float f; unsigned u; } v; v.f = f;
  unsigned r = v.u + 0x7FFFu + ((v.u >> 16) & 1u);
  return (unsigned short)(r >> 16);
}

__device__ __forceinline__ void async_lds16(void* lds, const void* g) {
  __builtin_amdgcn_global_load_lds(
      (const __attribute__((address_space(1))) unsigned int*)g,
      (__attribute__((address_space(3))) unsigned int*)lds, 16, 0, 0);
}

// ---------------- prep: pack W_big into K-panels [32][672][32] bf16 ----------------
__global__ void prep_w1(const float* __restrict__ Wc, const float* __restrict__ Wb,
                        const float* __restrict__ W1, unsigned short* __restrict__ Wp)
{
  int idx = blockIdx.x * 256 + threadIdx.x;      // < 672*1024
  int p   = idx / (N1_PAD * 32);
  int rem = idx % (N1_PAD * 32);
  int n   = rem >> 5;
  int kk  = rem & 31;
  int k   = p * 32 + kk;
  float w = 0.f;
  if (n < N_CLS)               w = Wc[(size_t)n * D_IN + k];
  else if (n < N_CLS + N_BOX)  w = Wb[(size_t)(n - N_CLS) * D_IN + k];
  else if (n < N1_USED)        w = W1[(size_t)(n - (N_CLS + N_BOX)) * D_IN + k];
  Wp[idx] = f2bf(w);
}

__global__ void prep_w23(const float* __restrict__ W2, const float* __restrict__ W3,
                         unsigned short* __restrict__ W2b, unsigned short* __restrict__ W3b)
{
  int idx = blockIdx.x * 256 + threadIdx.x;      // < 131072
  if (idx < 65536) W2b[idx] = f2bf(W2[idx]);
  else             W3b[idx - 65536] = f2bf(W3[idx - 65536]);
}

// ---------------- GEMM1: 64(M) x 336(N) per block, K=1024 ----------------
// Grid 4096 = 2048 M-tiles x 2 N-halves; XCD-chunk swizzle for L2/L3 reuse of x.
// 448 threads (7 waves), wave wc owns cols [wc*48,+48).
// BOTH operands staged via global_load_lds (A kept fp32 in LDS, 16 KB; B bf16,
// 43 KB; total 58 KB -> 2 blocks/CU). A's fp32->bf16 conversion happens at
// fragment-read time via v_cvt_pk_bf16_f32 (RNE) -- no register round-trip, no
// cross-step register state, no spill. All staging for step kp+1 is issued at
// the top of step kp and drained by the end-of-step barrier (full-step cover).
__global__ __launch_bounds__(448) void g1_kernel(
    const float* __restrict__ x, const unsigned short* __restrict__ Wp,
    const float* __restrict__ b_cls, const float* __restrict__ b_box,
    const float* __restrict__ b1,
    float* __restrict__ scores, float* __restrict__ deltas,
    unsigned short* __restrict__ h1)
{
  __shared__ __attribute__((aligned(16))) unsigned short Bs[2][NB_COLS * 32];  // 43 KB
  __shared__ __attribute__((aligned(16))) float          As[2][64 * 32];       // 16 KB

  const int tid  = threadIdx.x;
  const int wave = tid >> 6;
  const int lane = tid & 63;
  // bijective XCD-chunk swizzle (nwg = 4096, 4096 % 8 == 0)
  const int orig  = blockIdx.x;
  const int work  = (orig & 7) * 512 + (orig >> 3);
  const int m0    = (work >> 1) * 64;
  const int nbase = (work & 1) * NB_COLS;

  f32x4 acc[4][3];
#pragma unroll
  for (int i = 0; i < 4; ++i)
#pragma unroll
    for (int j = 0; j < 3; ++j)
      acc[i][j] = (f32x4){0.f, 0.f, 0.f, 0.f};

  // Unified async staging of one K-step: B = 1344 chunks, A = 512 chunks.
  // Chunk->wave mapping keeps the B/A split wave-uniform (1344 = 21 waves).
  auto stage = [&](int buf, int kp) {
    const unsigned short* wsrc = Wp + (size_t)kp * (N1_PAD * 32) + (size_t)nbase * 32;
#pragma unroll
    for (int i = 0; i < 5; ++i) {
      int c = tid + i * 448;
      if (c < 1344) {
        async_lds16((char*)&Bs[buf][0] + c * 16, (const char*)wsrc + c * 16);
      } else if (c < 1856) {
        int a = c - 1344;
        int row = a >> 3, q = a & 7;                 // 16-B quad within fp32 row
        async_lds16((char*)&As[buf][0] + a * 16,
                    (const char*)(x + (size_t)(m0 + row) * D_IN + (size_t)kp * 32 + q * 4));
      }
    }
  };

  stage(0, 0);
  __syncthreads();

  const int lr = lane & 15;
  const int g2 = (lane >> 4) * 8;    // fp32 element offset of this lane's k-octet

  union U8 { unsigned u[4]; short8 s; };

  for (int kp = 0; kp < 32; ++kp) {
    const int cur = kp & 1;
    if (kp < 31) stage(cur ^ 1, kp + 1);

    short8 af[4], bfr[3];
#pragma unroll
    for (int mi = 0; mi < 4; ++mi) {
      const float* base = &As[cur][(mi * 16 + lr) * 32 + g2];
      float4 p0 = *(const float4*)base;
      float4 p1 = *(const float4*)(base + 4);
      U8 t;
      asm("v_cvt_pk_bf16_f32 %0, %1, %2" : "=v"(t.u[0]) : "v"(p0.x), "v"(p0.y));
      asm("v_cvt_pk_bf16_f32 %0, %1, %2" : "=v"(t.u[1]) : "v"(p0.z), "v"(p0.w));
      asm("v_cvt_pk_bf16_f32 %0, %1, %2" : "=v"(t.u[2]) : "v"(p1.x), "v"(p1.y));
      asm("v_cvt_pk_bf16_f32 %0, %1, %2" : "=v"(t.u[3]) : "v"(p1.z), "v"(p1.w));
      af[mi] = t.s;
    }
#pragma unroll
    for (int ni = 0; ni < 3; ++ni)
      bfr[ni] = *(const short8*)&Bs[cur][(wave * 48 + ni * 16 + lr) * 32 + g2];
#pragma unroll
    for (int mi = 0; mi < 4; ++mi)
#pragma unroll
      for (int ni = 0; ni < 3; ++ni)
        acc[mi][ni] = __builtin_amdgcn_mfma_f32_16x16x32_bf16(af[mi], bfr[ni], acc[mi][ni], 0, 0, 0);

    __syncthreads();
  }

  // ---- epilogue: split cols into scores / deltas / h1 ----
  const int rbase = m0 + ((lane >> 4) << 2);
#pragma unroll
  for (int mi = 0; mi < 4; ++mi) {
#pragma unroll
    for (int ni = 0; ni < 3; ++ni) {
      int n = nbase + wave * 48 + ni * 16 + lr;
      if (n >= N1_USED) continue;
      if (n < N_CLS) {
        float bb = b_cls[n];
#pragma unroll
        for (int j = 0; j < 4; ++j) {
          int r = rbase + mi * 16 + j;
          scores[(size_t)r * N_CLS + n] = acc[mi][ni][j] + bb;
        }
      } else if (n < N_CLS + N_BOX) {
        int nb = n - N_CLS;
        float bb = b_box[nb];
#pragma unroll
        for (int j = 0; j < 4; ++j) {
          int r = rbase + mi * 16 + j;
          deltas[(size_t)r * N_BOX + nb] = acc[mi][ni][j] + bb;
        }
      } else {
        int nh = n - (N_CLS + N_BOX);
        float bb = b1[nh];
#pragma unroll
        for (int j = 0; j < 4; ++j) {
          int r = rbase + mi * 16 + j;
          float h = acc[mi][ni][j] + bb;
          h1[(size_t)r * N_H + nh] = f2bf(fmaxf(h, 0.f));
        }
      }
    }
  }
}

// ---------------- GEMM2/3: full-row blocks, 128(M) x 256(N=all), K=256, BK=32 ----
// 512 threads (8 waves), wave (wm,wn) = (wave>>2, wave&3), per-wave 64x64 output.
// Each block reads ONLY A rows [m0,m0+128) and writes ONLY those rows ->
// in-place (out==A) is block-local and race-free. Grid is (R/128, 1).
__device__ __forceinline__ void g23_stage(unsigned short* Asb, unsigned short* Bsb,
    const unsigned short* __restrict__ A, const unsigned short* __restrict__ Bw,
    int m0, int kp, int tid)
{
  {
    int row = tid >> 2, kq = tid & 3;             // A: 512 chunks of 16B
    async_lds16((char*)Asb + tid * 16,
                (const char*)(A + (size_t)(m0 + row) * N_H + (size_t)kp * 32 + kq * 8));
  }
#pragma unroll
  for (int i = 0; i < 2; ++i) {                   // B: 1024 chunks of 16B
    int chunk = tid + i * 512;
    int row = chunk >> 2, kq = chunk & 3;
    async_lds16((char*)Bsb + chunk * 16,
                (const char*)(Bw + (size_t)row * N_H + (size_t)kp * 32 + kq * 8));
  }
}

template <int RELU, int OUT_BF16>
__global__ __launch_bounds__(512, 1) void g23_kernel(
    const unsigned short* __restrict__ A, const unsigned short* __restrict__ Bw,
    const float* __restrict__ bias, void* __restrict__ outv)
{
  __shared__ __attribute__((aligned(16))) unsigned short As[2][128 * 32];
  __shared__ __attribute__((aligned(16))) unsigned short Bs[2][256 * 32];
  const int tid  = threadIdx.x;
  const int wave = tid >> 6, lane = tid & 63;
  const int wm = wave >> 2, wn = wave & 3;
  const int m0 = blockIdx.x * 128;

  f32x4 acc[4][4];
#pragma unroll
  for (int i = 0; i < 4; ++i)
#pragma unroll
    for (int j = 0; j < 4; ++j)
      acc[i][j] = (f32x4){0.f, 0.f, 0.f, 0.f};

  g23_stage(&As[0][0], &Bs[0][0], A, Bw, m0, 0, tid);
  __syncthreads();

  const int lr = lane & 15;
  const int lk = (lane >> 4) * 8;

  for (int kp = 0; kp < 8; ++kp) {
    const int cur = kp & 1, nxt = cur ^ 1;
    if (kp < 7) g23_stage(&As[nxt][0], &Bs[nxt][0], A, Bw, m0, kp + 1, tid);

    short8 af[4], bfr[4];
#pragma unroll
    for (int mi = 0; mi < 4; ++mi)
      af[mi] = *(const short8*)&As[cur][(wm * 64 + mi * 16 + lr) * 32 + lk];
#pragma unroll
    for (int ni = 0; ni < 4; ++ni)
      bfr[ni] = *(const short8*)&Bs[cur][(wn * 64 + ni * 16 + lr) * 32 + lk];
#pragma unroll
    for (int mi = 0; mi < 4; ++mi)
#pragma unroll
      for (int ni = 0; ni < 4; ++ni)
        acc[mi][ni] = __builtin_amdgcn_mfma_f32_16x16x32_bf16(af[mi], bfr[ni], acc[mi][ni], 0, 0, 0);
    __syncthreads();
  }

  // All LDS reads of A done; safe to overwrite our own rows (even if out==A).
#pragma unroll
  for (int mi = 0; mi < 4; ++mi) {
#pragma unroll
    for (int ni = 0; ni < 4; ++ni) {
      int n = wn * 64 + ni * 16 + lr;
      float bb = bias[n];
#pragma unroll
      for (int j = 0; j < 4; ++j) {
        int r = m0 + wm * 64 + mi * 16 + ((lane >> 4) << 2) + j;
        float v = acc[mi][ni][j] + bb;
        if (RELU) v = fmaxf(v, 0.f);
        if (OUT_BF16) ((unsigned short*)outv)[(size_t)r * N_H + n] = f2bf(v);
        else          ((float*)outv)[(size_t)r * N_H + n] = v;
      }
    }
  }
}

// ---------------- launch ----------------
extern "C" void kernel_launch(void* const* d_in, const int* in_sizes, int n_in,
                              void* d_out, int out_size, void* d_ws, size_t ws_size,
                              hipStream_t stream)
{
  const float* x     = (const float*)d_in[0];
  const float* W_cls = (const float*)d_in[1];
  const float* b_cls = (const float*)d_in[2];
  const float* W_box = (const float*)d_in[3];
  const float* b_box = (const float*)d_in[4];
  const float* W1    = (const float*)d_in[5];
  const float* b1    = (const float*)d_in[6];
  const float* W2    = (const float*)d_in[7];
  const float* b2    = (const float*)d_in[8];
  const float* W3    = (const float*)d_in[9];
  const float* b3    = (const float*)d_in[10];

  float* scores = (float*)d_out;
  float* deltas = scores + (size_t)R_TOT * N_CLS;
  float* embeds = deltas + (size_t)R_TOT * N_BOX;

  // Scratch layout (total ~65.6 MB):
  //   Wp  : 672*1024 bf16      = 1,376,256 B
  //   W2b :  65536 bf16        =   131,072 B
  //   W3b :  65536 bf16        =   131,072 B
  //   h   : 131072*256 bf16    = 67,108,864 B  (h1; GEMM2 overwrites in place -> h2)
  char* ws = (char*)d_ws;
  unsigned short* Wp  = (unsigned short*)ws;
  unsigned short* W2b = (unsigned short*)(ws + 1376256);
  unsigned short* W3b = (unsigned short*)(ws + 1376256 + 131072);
  unsigned short* h   = (unsigned short*)(ws + 1638400);

  hipLaunchKernelGGL(prep_w1, dim3(2688), dim3(256), 0, stream, W_cls, W_box, W1, Wp);
  hipLaunchKernelGGL(prep_w23, dim3(512), dim3(256), 0, stream, W2, W3, W2b, W3b);
  hipLaunchKernelGGL(g1_kernel, dim3(4096), dim3(448), 0, stream,
                     x, Wp, b_cls, b_box, b1, scores, deltas, h);
  hipLaunchKernelGGL((g23_kernel<1, 1>), dim3(R_TOT / 128), dim3(512), 0, stream,
                     h, W2b, b2, (void*)h);       // in place: h1 -> h2 (block-local rows)
  hipLaunchKernelGGL((g23_kernel<0, 0>), dim3(R_TOT / 128), dim3(512), 0, stream,
                     h, W3b, b3, (void*)embeds);
}

// Round 12
// 488.162 us; speedup vs baseline: 1.3750x; 1.0795x over previous
//
#include <hip/hip_runtime.h>
#include <hip/hip_bf16.h>
#include <stdint.h>

#define R_TOT   131072
#define D_IN    1024
#define N_CLS   81
#define N_BOX   320
#define N_H     256
#define N1_USED 657
#define N1_PAD  672
#define NB_COLS 224   // per-block N (third of 672)

typedef __attribute__((ext_vector_type(8))) short short8;
typedef __attribute__((ext_vector_type(4))) float f32x4;

__device__ __forceinline__ unsigned short f2bf(float f) {
  union { float f; unsigned u; } v; v.f = f;
  unsigned r = v.u + 0x7FFFu + ((v.u >> 16) & 1u);
  return (unsigned short)(r >> 16);
}

__device__ __forceinline__ void async_lds16(void* lds, const void* g) {
  __builtin_amdgcn_global_load_lds(
      (const __attribute__((address_space(1))) unsigned int*)g,
      (__attribute__((address_space(3))) unsigned int*)lds, 16, 0, 0);
}

// ---------------- prep: pack W_big into K-panels [32][672][32] bf16 ----------------
// B-swizzle baked into the layout: row n stores its k-octets XOR-permuted by
// ((n>>1)&3) so g1's ds_read_b128 across 16 consecutive cols hits 8 distinct
// 4-bank granules (2-way aliasing = free) instead of 2 (8-way conflict).
__global__ void prep_w1(const float* __restrict__ Wc, const float* __restrict__ Wb,
                        const float* __restrict__ W1, unsigned short* __restrict__ Wp)
{
  int idx = blockIdx.x * 256 + threadIdx.x;      // < 672*1024
  int p   = idx / (N1_PAD * 32);
  int rem = idx % (N1_PAD * 32);
  int n   = rem >> 5;
  int kk  = rem & 31;
  int k   = p * 32 + (kk ^ (((n >> 1) & 3) << 3));   // value fetched from swizzled slot
  float w = 0.f;
  if (n < N_CLS)               w = Wc[(size_t)n * D_IN + k];
  else if (n < N_CLS + N_BOX)  w = Wb[(size_t)(n - N_CLS) * D_IN + k];
  else if (n < N1_USED)        w = W1[(size_t)(n - (N_CLS + N_BOX)) * D_IN + k];
  Wp[idx] = f2bf(w);
}

__global__ void prep_w23(const float* __restrict__ W2, const float* __restrict__ W3,
                         unsigned short* __restrict__ W2b, unsigned short* __restrict__ W3b)
{
  int idx = blockIdx.x * 256 + threadIdx.x;      // < 131072
  if (idx < 65536) W2b[idx] = f2bf(W2[idx]);
  else             W3b[idx - 65536] = f2bf(W3[idx - 65536]);
}

// ---------------- GEMM1: 64(M) x 224(N) per block, K=1024 ----------------
// Grid 6144 = 2048 M-tiles x 3 N-panels; bijective XCD swizzle keeps a tile's
// panels temporally adjacent on one XCD (x re-reads hit L2/L3).
// 448 threads (7 waves), wave wc owns cols [wc*32,+32). LDS 44 KB -> 3 blocks/CU.
// A staged fp32 via global_load_lds with slot-XOR swizzle (linear LDS dest,
// inverse-swizzled global source, swizzled read -> 2-way); converted to bf16 at
// fragment-read time via v_cvt_pk_bf16_f32. B staged linearly (swizzle baked
// into Wp by prep_w1), read with the matching XOR.
__global__ __launch_bounds__(448) void g1_kernel(
    const float* __restrict__ x, const unsigned short* __restrict__ Wp,
    const float* __restrict__ b_cls, const float* __restrict__ b_box,
    const float* __restrict__ b1,
    float* __restrict__ scores, float* __restrict__ deltas,
    unsigned short* __restrict__ h1)
{
  __shared__ __attribute__((aligned(16))) unsigned short Bs[2][NB_COLS * 32];  // 28 KB
  __shared__ __attribute__((aligned(16))) float          As[2][64 * 32];       // 16 KB

  const int tid  = threadIdx.x;
  const int wave = tid >> 6;
  const int lane = tid & 63;
  // bijective XCD-chunk swizzle (nwg = 6144, 6144 % 8 == 0)
  const int orig  = blockIdx.x;
  const int work  = (orig & 7) * 768 + (orig >> 3);
  const int m0    = (work / 3) * 64;
  const int nbase = (work % 3) * NB_COLS;

  f32x4 acc[4][2];
#pragma unroll
  for (int i = 0; i < 4; ++i)
#pragma unroll
    for (int j = 0; j < 2; ++j)
      acc[i][j] = (f32x4){0.f, 0.f, 0.f, 0.f};

  // Staging one K-step: B = 896 chunks (linear), A = 512 chunks (src-swizzled).
  // Region boundaries 896 = 14*64 and 1408 = 22*64 are wave-aligned.
  auto stage = [&](int buf, int kp) {
    const unsigned short* wsrc = Wp + (size_t)kp * (N1_PAD * 32) + (size_t)nbase * 32;
#pragma unroll
    for (int i = 0; i < 4; ++i) {
      int c = tid + i * 448;
      if (c < 896) {
        async_lds16((char*)&Bs[buf][0] + c * 16, (const char*)wsrc + c * 16);
      } else if (c < 1408) {
        int a = c - 896;
        int row = a >> 3, q = a & 7;               // 16-B slot within fp32 row
        async_lds16((char*)&As[buf][0] + a * 16,
                    (const char*)(x + (size_t)(m0 + row) * D_IN + (size_t)kp * 32
                                    + ((q ^ (row & 7)) << 2)));
      }
    }
  };

  stage(0, 0);
  __syncthreads();

  const int lr = lane & 15;
  const int g2 = (lane >> 4) * 8;    // element offset of this lane's k-octet

  union U8 { unsigned u[4]; short8 s; };

  for (int kp = 0; kp < 32; ++kp) {
    const int cur = kp & 1;
    if (kp < 31) stage(cur ^ 1, kp + 1);

    short8 af[4], bfr[2];
#pragma unroll
    for (int mi = 0; mi < 4; ++mi) {
      const int r = mi * 16 + lr;
      const char* Abase = (const char*)&As[cur][0] + r * 128;
      const int s0 = g2 >> 2;                      // {0,2,4,6}
      float4 p0 = *(const float4*)(Abase + (((s0    ) ^ (r & 7)) << 4));
      float4 p1 = *(const float4*)(Abase + (((s0 + 1) ^ (r & 7)) << 4));
      U8 t;
      asm("v_cvt_pk_bf16_f32 %0, %1, %2" : "=v"(t.u[0]) : "v"(p0.x), "v"(p0.y));
      asm("v_cvt_pk_bf16_f32 %0, %1, %2" : "=v"(t.u[1]) : "v"(p0.z), "v"(p0.w));
      asm("v_cvt_pk_bf16_f32 %0, %1, %2" : "=v"(t.u[2]) : "v"(p1.x), "v"(p1.y));
      asm("v_cvt_pk_bf16_f32 %0, %1, %2" : "=v"(t.u[3]) : "v"(p1.z), "v"(p1.w));
      af[mi] = t.s;
    }
#pragma unroll
    for (int ni = 0; ni < 2; ++ni) {
      const int c = wave * 32 + ni * 16 + lr;
      bfr[ni] = *(const short8*)&Bs[cur][c * 32 + (g2 ^ (((c >> 1) & 3) << 3))];
    }
#pragma unroll
    for (int mi = 0; mi < 4; ++mi)
#pragma unroll
      for (int ni = 0; ni < 2; ++ni)
        acc[mi][ni] = __builtin_amdgcn_mfma_f32_16x16x32_bf16(af[mi], bfr[ni], acc[mi][ni], 0, 0, 0);

    __syncthreads();
  }

  // ---- epilogue: split cols into scores / deltas / h1 ----
  const int rbase = m0 + ((lane >> 4) << 2);
#pragma unroll
  for (int mi = 0; mi < 4; ++mi) {
#pragma unroll
    for (int ni = 0; ni < 2; ++ni) {
      int n = nbase + wave * 32 + ni * 16 + lr;
      if (n >= N1_USED) continue;
      if (n < N_CLS) {
        float bb = b_cls[n];
#pragma unroll
        for (int j = 0; j < 4; ++j) {
          int r = rbase + mi * 16 + j;
          scores[(size_t)r * N_CLS + n] = acc[mi][ni][j] + bb;
        }
      } else if (n < N_CLS + N_BOX) {
        int nb = n - N_CLS;
        float bb = b_box[nb];
#pragma unroll
        for (int j = 0; j < 4; ++j) {
          int r = rbase + mi * 16 + j;
          deltas[(size_t)r * N_BOX + nb] = acc[mi][ni][j] + bb;
        }
      } else {
        int nh = n - (N_CLS + N_BOX);
        float bb = b1[nh];
#pragma unroll
        for (int j = 0; j < 4; ++j) {
          int r = rbase + mi * 16 + j;
          float h = acc[mi][ni][j] + bb;
          h1[(size_t)r * N_H + nh] = f2bf(fmaxf(h, 0.f));
        }
      }
    }
  }
}

// ---------------- GEMM2/3: full-row blocks, 128(M) x 256(N=all), K=256, BK=32 ----
// 512 threads (8 waves), wave (wm,wn) = (wave>>2, wave&3), per-wave 64x64 output.
// Each block reads ONLY A rows [m0,m0+128) and writes ONLY those rows ->
// in-place (out==A) is block-local and race-free. Grid is (R/128, 1).
__device__ __forceinline__ void g23_stage(unsigned short* Asb, unsigned short* Bsb,
    const unsigned short* __restrict__ A, const unsigned short* __restrict__ Bw,
    int m0, int kp, int tid)
{
  {
    int row = tid >> 2, kq = tid & 3;             // A: 512 chunks of 16B
    async_lds16((char*)Asb + tid * 16,
                (const char*)(A + (size_t)(m0 + row) * N_H + (size_t)kp * 32 + kq * 8));
  }
#pragma unroll
  for (int i = 0; i < 2; ++i) {                   // B: 1024 chunks of 16B
    int chunk = tid + i * 512;
    int row = chunk >> 2, kq = chunk & 3;
    async_lds16((char*)Bsb + chunk * 16,
                (const char*)(Bw + (size_t)row * N_H + (size_t)kp * 32 + kq * 8));
  }
}

template <int RELU, int OUT_BF16>
__global__ __launch_bounds__(512, 1) void g23_kernel(
    const unsigned short* __restrict__ A, const unsigned short* __restrict__ Bw,
    const float* __restrict__ bias, void* __restrict__ outv)
{
  __shared__ __attribute__((aligned(16))) unsigned short As[2][128 * 32];
  __shared__ __attribute__((aligned(16))) unsigned short Bs[2][256 * 32];
  const int tid  = threadIdx.x;
  const int wave = tid >> 6, lane = tid & 63;
  const int wm = wave >> 2, wn = wave & 3;
  const int m0 = blockIdx.x * 128;

  f32x4 acc[4][4];
#pragma unroll
  for (int i = 0; i < 4; ++i)
#pragma unroll
    for (int j = 0; j < 4; ++j)
      acc[i][j] = (f32x4){0.f, 0.f, 0.f, 0.f};

  g23_stage(&As[0][0], &Bs[0][0], A, Bw, m0, 0, tid);
  __syncthreads();

  const int lr = lane & 15;
  const int lk = (lane >> 4) * 8;

  for (int kp = 0; kp < 8; ++kp) {
    const int cur = kp & 1, nxt = cur ^ 1;
    if (kp < 7) g23_stage(&As[nxt][0], &Bs[nxt][0], A, Bw, m0, kp + 1, tid);

    short8 af[4], bfr[4];
#pragma unroll
    for (int mi = 0; mi < 4; ++mi)
      af[mi] = *(const short8*)&As[cur][(wm * 64 + mi * 16 + lr) * 32 + lk];
#pragma unroll
    for (int ni = 0; ni < 4; ++ni)
      bfr[ni] = *(const short8*)&Bs[cur][(wn * 64 + ni * 16 + lr) * 32 + lk];
#pragma unroll
    for (int mi = 0; mi < 4; ++mi)
#pragma unroll
      for (int ni = 0; ni < 4; ++ni)
        acc[mi][ni] = __builtin_amdgcn_mfma_f32_16x16x32_bf16(af[mi], bfr[ni], acc[mi][ni], 0, 0, 0);
    __syncthreads();
  }

  // All LDS reads of A done; safe to overwrite our own rows (even if out==A).
#pragma unroll
  for (int mi = 0; mi < 4; ++mi) {
#pragma unroll
    for (int ni = 0; ni < 4; ++ni) {
      int n = wn * 64 + ni * 16 + lr;
      float bb = bias[n];
#pragma unroll
      for (int j = 0; j < 4; ++j) {
        int r = m0 + wm * 64 + mi * 16 + ((lane >> 4) << 2) + j;
        float v = acc[mi][ni][j] + bb;
        if (RELU) v = fmaxf(v, 0.f);
        if (OUT_BF16) ((unsigned short*)outv)[(size_t)r * N_H + n] = f2bf(v);
        else          ((float*)outv)[(size_t)r * N_H + n] = v;
      }
    }
  }
}

// ---------------- launch ----------------
extern "C" void kernel_launch(void* const* d_in, const int* in_sizes, int n_in,
                              void* d_out, int out_size, void* d_ws, size_t ws_size,
                              hipStream_t stream)
{
  const float* x     = (const float*)d_in[0];
  const float* W_cls = (const float*)d_in[1];
  const float* b_cls = (const float*)d_in[2];
  const float* W_box = (const float*)d_in[3];
  const float* b_box = (const float*)d_in[4];
  const float* W1    = (const float*)d_in[5];
  const float* b1    = (const float*)d_in[6];
  const float* W2    = (const float*)d_in[7];
  const float* b2    = (const float*)d_in[8];
  const float* W3    = (const float*)d_in[9];
  const float* b3    = (const float*)d_in[10];

  float* scores = (float*)d_out;
  float* deltas = scores + (size_t)R_TOT * N_CLS;
  float* embeds = deltas + (size_t)R_TOT * N_BOX;

  // Scratch layout (total ~65.6 MB):
  //   Wp  : 672*1024 bf16      = 1,376,256 B   (B-swizzled layout)
  //   W2b :  65536 bf16        =   131,072 B
  //   W3b :  65536 bf16        =   131,072 B
  //   h   : 131072*256 bf16    = 67,108,864 B  (h1; GEMM2 overwrites in place -> h2)
  char* ws = (char*)d_ws;
  unsigned short* Wp  = (unsigned short*)ws;
  unsigned short* W2b = (unsigned short*)(ws + 1376256);
  unsigned short* W3b = (unsigned short*)(ws + 1376256 + 131072);
  unsigned short* h   = (unsigned short*)(ws + 1638400);

  hipLaunchKernelGGL(prep_w1, dim3(2688), dim3(256), 0, stream, W_cls, W_box, W1, Wp);
  hipLaunchKernelGGL(prep_w23, dim3(512), dim3(256), 0, stream, W2, W3, W2b, W3b);
  hipLaunchKernelGGL(g1_kernel, dim3(6144), dim3(448), 0, stream,
                     x, Wp, b_cls, b_box, b1, scores, deltas, h);
  hipLaunchKernelGGL((g23_kernel<1, 1>), dim3(R_TOT / 128), dim3(512), 0, stream,
                     h, W2b, b2, (void*)h);       // in place: h1 -> h2 (block-local rows)
  hipLaunchKernelGGL((g23_kernel<0, 0>), dim3(R_TOT / 128), dim3(512), 0, stream,
                     h, W3b, b3, (void*)embeds);
}

// Round 13
// 485.517 us; speedup vs baseline: 1.3825x; 1.0054x over previous
//
#include <hip/hip_runtime.h>
#include <hip/hip_bf16.h>
#include <stdint.h>

#define R_TOT   131072
#define D_IN    1024
#define N_CLS   81
#define N_BOX   320
#define N_H     256
#define N1_USED 657
#define N1_PAD  672
#define NB_COLS 224   // per-block N (third of 672)

typedef __attribute__((ext_vector_type(8))) short short8;
typedef __attribute__((ext_vector_type(4))) float f32x4;

__device__ __forceinline__ unsigned short f2bf(float f) {
  union { float f; unsigned u; } v; v.f = f;
  unsigned r = v.u + 0x7FFFu + ((v.u >> 16) & 1u);
  return (unsigned short)(r >> 16);
}

__device__ __forceinline__ void async_lds16(void* lds, const void* g) {
  __builtin_amdgcn_global_load_lds(
      (const __attribute__((address_space(1))) unsigned int*)g,
      (__attribute__((address_space(3))) unsigned int*)lds, 16, 0, 0);
}

// ---------------- prep: pack W_big into K-panels [32][672][32] bf16 ----------------
// B-swizzle baked into the layout: row n stores its k-octets XOR-permuted by
// ((n>>1)&3) so g1's ds_read_b128 across 16 consecutive cols spreads over 8
// 4-bank granules (throughput-minimum 2-way aliasing).
__global__ void prep_w1(const float* __restrict__ Wc, const float* __restrict__ Wb,
                        const float* __restrict__ W1, unsigned short* __restrict__ Wp)
{
  int idx = blockIdx.x * 256 + threadIdx.x;      // < 672*1024
  int p   = idx / (N1_PAD * 32);
  int rem = idx % (N1_PAD * 32);
  int n   = rem >> 5;
  int kk  = rem & 31;
  int k   = p * 32 + (kk ^ (((n >> 1) & 3) << 3));   // value fetched from swizzled slot
  float w = 0.f;
  if (n < N_CLS)               w = Wc[(size_t)n * D_IN + k];
  else if (n < N_CLS + N_BOX)  w = Wb[(size_t)(n - N_CLS) * D_IN + k];
  else if (n < N1_USED)        w = W1[(size_t)(n - (N_CLS + N_BOX)) * D_IN + k];
  Wp[idx] = f2bf(w);
}

__global__ void prep_w23(const float* __restrict__ W2, const float* __restrict__ W3,
                         unsigned short* __restrict__ W2b, unsigned short* __restrict__ W3b)
{
  int idx = blockIdx.x * 256 + threadIdx.x;      // < 131072
  if (idx < 65536) W2b[idx] = f2bf(W2[idx]);
  else             W3b[idx - 65536] = f2bf(W3[idx - 65536]);
}

// ---------------- GEMM1: 64(M) x 224(N) per block, K=1024 ----------------
// Grid 6144 = 2048 M-tiles x 3 N-panels; bijective XCD swizzle; 448 thr (7 waves),
// wave wc owns cols [wc*32,+32). LDS 44 KB -> 3 blocks/CU.
// COUNTED-VMCNT PIPELINE (T4): two stages always in flight; per step
//   s_waitcnt vmcnt(L) [L = this wave's loads/stage] -> s_barrier ->
//   frag reads -> lgkmcnt(0)+sched_barrier -> s_barrier -> restage(kp+2) -> MFMA.
// Never drains to 0 inside the loop; stage(kp) issued at step kp-2 (full-step cover).
// Per-wave loads/stage: wave 0 = 4 (extra A chunk), waves 1-6 = 3 (wave-uniform).
__global__ __launch_bounds__(448) void g1_kernel(
    const float* __restrict__ x, const unsigned short* __restrict__ Wp,
    const float* __restrict__ b_cls, const float* __restrict__ b_box,
    const float* __restrict__ b1,
    float* __restrict__ scores, float* __restrict__ deltas,
    unsigned short* __restrict__ h1)
{
  __shared__ __attribute__((aligned(16))) unsigned short Bs[2][NB_COLS * 32];  // 28 KB
  __shared__ __attribute__((aligned(16))) float          As[2][64 * 32];       // 16 KB

  const int tid  = threadIdx.x;
  const int wave = tid >> 6;
  const int lane = tid & 63;
  // bijective XCD-chunk swizzle (nwg = 6144, 6144 % 8 == 0)
  const int orig  = blockIdx.x;
  const int work  = (orig & 7) * 768 + (orig >> 3);
  const int m0    = (work / 3) * 64;
  const int nbase = (work % 3) * NB_COLS;

  f32x4 acc[4][2];
#pragma unroll
  for (int i = 0; i < 4; ++i)
#pragma unroll
    for (int j = 0; j < 2; ++j)
      acc[i][j] = (f32x4){0.f, 0.f, 0.f, 0.f};

  // Staging one K-step: B = 896 chunks (linear; swizzle baked into Wp),
  // A = 512 chunks (inverse-swizzled global source, linear LDS dest).
  auto stage = [&](int buf, int kp) {
    const unsigned short* wsrc = Wp + (size_t)kp * (N1_PAD * 32) + (size_t)nbase * 32;
#pragma unroll
    for (int i = 0; i < 4; ++i) {
      int c = tid + i * 448;
      if (c < 896) {
        async_lds16((char*)&Bs[buf][0] + c * 16, (const char*)wsrc + c * 16);
      } else if (c < 1408) {
        int a = c - 896;
        int row = a >> 3, q = a & 7;               // 16-B slot within fp32 row
        async_lds16((char*)&As[buf][0] + a * 16,
                    (const char*)(x + (size_t)(m0 + row) * D_IN + (size_t)kp * 32
                                    + ((q ^ (row & 7)) << 2)));
      }
    }
  };

  // prologue: two stages in flight, no drain
  stage(0, 0);
  stage(1, 1);

  const int lr = lane & 15;
  const int g2 = (lane >> 4) * 8;    // element offset of this lane's k-octet

  union U8 { unsigned u[4]; short8 s; };

  for (int kp = 0; kp < 32; ++kp) {
    const int cur = kp & 1;

    // wait ONLY for buf[cur]'s stage (issued 2 steps ago); keep next in flight
    if (kp == 31)       asm volatile("s_waitcnt vmcnt(0)" ::: "memory");
    else if (wave == 0) asm volatile("s_waitcnt vmcnt(4)" ::: "memory");
    else                asm volatile("s_waitcnt vmcnt(3)" ::: "memory");
    __builtin_amdgcn_s_barrier();

    // ---- fragment reads from buf[cur] ----
    short8 af[4], bfr[2];
#pragma unroll
    for (int mi = 0; mi < 4; ++mi) {
      const int r = mi * 16 + lr;
      const char* Abase = (const char*)&As[cur][0] + r * 128;
      const int s0 = g2 >> 2;                      // {0,2,4,6}
      float4 p0 = *(const float4*)(Abase + (((s0    ) ^ (r & 7)) << 4));
      float4 p1 = *(const float4*)(Abase + (((s0 + 1) ^ (r & 7)) << 4));
      U8 t;
      asm("v_cvt_pk_bf16_f32 %0, %1, %2" : "=v"(t.u[0]) : "v"(p0.x), "v"(p0.y));
      asm("v_cvt_pk_bf16_f32 %0, %1, %2" : "=v"(t.u[1]) : "v"(p0.z), "v"(p0.w));
      asm("v_cvt_pk_bf16_f32 %0, %1, %2" : "=v"(t.u[2]) : "v"(p1.x), "v"(p1.y));
      asm("v_cvt_pk_bf16_f32 %0, %1, %2" : "=v"(t.u[3]) : "v"(p1.z), "v"(p1.w));
      af[mi] = t.s;
    }
#pragma unroll
    for (int ni = 0; ni < 2; ++ni) {
      const int c = wave * 32 + ni * 16 + lr;
      bfr[ni] = *(const short8*)&Bs[cur][c * 32 + (g2 ^ (((c >> 1) & 3) << 3))];
    }

    // all waves done reading buf[cur] before it is restaged
    asm volatile("s_waitcnt lgkmcnt(0)" ::: "memory");
    __builtin_amdgcn_sched_barrier(0);
    __builtin_amdgcn_s_barrier();

    if (kp + 2 < 32) stage(cur, kp + 2);   // overwrite freed buffer; lands at kp+2

#pragma unroll
    for (int mi = 0; mi < 4; ++mi)
#pragma unroll
      for (int ni = 0; ni < 2; ++ni)
        acc[mi][ni] = __builtin_amdgcn_mfma_f32_16x16x32_bf16(af[mi], bfr[ni], acc[mi][ni], 0, 0, 0);
  }

  // ---- epilogue: split cols into scores / deltas / h1 ----
  const int rbase = m0 + ((lane >> 4) << 2);
#pragma unroll
  for (int mi = 0; mi < 4; ++mi) {
#pragma unroll
    for (int ni = 0; ni < 2; ++ni) {
      int n = nbase + wave * 32 + ni * 16 + lr;
      if (n >= N1_USED) continue;
      if (n < N_CLS) {
        float bb = b_cls[n];
#pragma unroll
        for (int j = 0; j < 4; ++j) {
          int r = rbase + mi * 16 + j;
          scores[(size_t)r * N_CLS + n] = acc[mi][ni][j] + bb;
        }
      } else if (n < N_CLS + N_BOX) {
        int nb = n - N_CLS;
        float bb = b_box[nb];
#pragma unroll
        for (int j = 0; j < 4; ++j) {
          int r = rbase + mi * 16 + j;
          deltas[(size_t)r * N_BOX + nb] = acc[mi][ni][j] + bb;
        }
      } else {
        int nh = n - (N_CLS + N_BOX);
        float bb = b1[nh];
#pragma unroll
        for (int j = 0; j < 4; ++j) {
          int r = rbase + mi * 16 + j;
          float h = acc[mi][ni][j] + bb;
          h1[(size_t)r * N_H + nh] = f2bf(fmaxf(h, 0.f));
        }
      }
    }
  }
}

// ---------------- GEMM2/3: full-row blocks, 128(M) x 256(N=all), K=256, BK=32 ----
// 512 threads (8 waves), wave (wm,wn) = (wave>>2, wave&3), per-wave 64x64 output.
// Each block reads ONLY A rows [m0,m0+128) and writes ONLY those rows ->
// in-place (out==A) is block-local and race-free. Grid is (R/128, 1).
__device__ __forceinline__ void g23_stage(unsigned short* Asb, unsigned short* Bsb,
    const unsigned short* __restrict__ A, const unsigned short* __restrict__ Bw,
    int m0, int kp, int tid)
{
  {
    int row = tid >> 2, kq = tid & 3;             // A: 512 chunks of 16B
    async_lds16((char*)Asb + tid * 16,
                (const char*)(A + (size_t)(m0 + row) * N_H + (size_t)kp * 32 + kq * 8));
  }
#pragma unroll
  for (int i = 0; i < 2; ++i) {                   // B: 1024 chunks of 16B
    int chunk = tid + i * 512;
    int row = chunk >> 2, kq = chunk & 3;
    async_lds16((char*)Bsb + chunk * 16,
                (const char*)(Bw + (size_t)row * N_H + (size_t)kp * 32 + kq * 8));
  }
}

template <int RELU, int OUT_BF16>
__global__ __launch_bounds__(512, 1) void g23_kernel(
    const unsigned short* __restrict__ A, const unsigned short* __restrict__ Bw,
    const float* __restrict__ bias, void* __restrict__ outv)
{
  __shared__ __attribute__((aligned(16))) unsigned short As[2][128 * 32];
  __shared__ __attribute__((aligned(16))) unsigned short Bs[2][256 * 32];
  const int tid  = threadIdx.x;
  const int wave = tid >> 6, lane = tid & 63;
  const int wm = wave >> 2, wn = wave & 3;
  const int m0 = blockIdx.x * 128;

  f32x4 acc[4][4];
#pragma unroll
  for (int i = 0; i < 4; ++i)
#pragma unroll
    for (int j = 0; j < 4; ++j)
      acc[i][j] = (f32x4){0.f, 0.f, 0.f, 0.f};

  g23_stage(&As[0][0], &Bs[0][0], A, Bw, m0, 0, tid);
  __syncthreads();

  const int lr = lane & 15;
  const int lk = (lane >> 4) * 8;

  for (int kp = 0; kp < 8; ++kp) {
    const int cur = kp & 1, nxt = cur ^ 1;
    if (kp < 7) g23_stage(&As[nxt][0], &Bs[nxt][0], A, Bw, m0, kp + 1, tid);

    short8 af[4], bfr[4];
#pragma unroll
    for (int mi = 0; mi < 4; ++mi)
      af[mi] = *(const short8*)&As[cur][(wm * 64 + mi * 16 + lr) * 32 + lk];
#pragma unroll
    for (int ni = 0; ni < 4; ++ni)
      bfr[ni] = *(const short8*)&Bs[cur][(wn * 64 + ni * 16 + lr) * 32 + lk];
#pragma unroll
    for (int mi = 0; mi < 4; ++mi)
#pragma unroll
      for (int ni = 0; ni < 4; ++ni)
        acc[mi][ni] = __builtin_amdgcn_mfma_f32_16x16x32_bf16(af[mi], bfr[ni], acc[mi][ni], 0, 0, 0);
    __syncthreads();
  }

  // All LDS reads of A done; safe to overwrite our own rows (even if out==A).
#pragma unroll
  for (int mi = 0; mi < 4; ++mi) {
#pragma unroll
    for (int ni = 0; ni < 4; ++ni) {
      int n = wn * 64 + ni * 16 + lr;
      float bb = bias[n];
#pragma unroll
      for (int j = 0; j < 4; ++j) {
        int r = m0 + wm * 64 + mi * 16 + ((lane >> 4) << 2) + j;
        float v = acc[mi][ni][j] + bb;
        if (RELU) v = fmaxf(v, 0.f);
        if (OUT_BF16) ((unsigned short*)outv)[(size_t)r * N_H + n] = f2bf(v);
        else          ((float*)outv)[(size_t)r * N_H + n] = v;
      }
    }
  }
}

// ---------------- launch ----------------
extern "C" void kernel_launch(void* const* d_in, const int* in_sizes, int n_in,
                              void* d_out, int out_size, void* d_ws, size_t ws_size,
                              hipStream_t stream)
{
  const float* x     = (const float*)d_in[0];
  const float* W_cls = (const float*)d_in[1];
  const float* b_cls = (const float*)d_in[2];
  const float* W_box = (const float*)d_in[3];
  const float* b_box = (const float*)d_in[4];
  const float* W1    = (const float*)d_in[5];
  const float* b1    = (const float*)d_in[6];
  const float* W2    = (const float*)d_in[7];
  const float* b2    = (const float*)d_in[8];
  const float* W3    = (const float*)d_in[9];
  const float* b3    = (const float*)d_in[10];

  float* scores = (float*)d_out;
  float* deltas = scores + (size_t)R_TOT * N_CLS;
  float* embeds = deltas + (size_t)R_TOT * N_BOX;

  // Scratch layout (total ~65.6 MB):
  //   Wp  : 672*1024 bf16      = 1,376,256 B   (B-swizzled layout)
  //   W2b :  65536 bf16        =   131,072 B
  //   W3b :  65536 bf16        =   131,072 B
  //   h   : 131072*256 bf16    = 67,108,864 B  (h1; GEMM2 overwrites in place -> h2)
  char* ws = (char*)d_ws;
  unsigned short* Wp  = (unsigned short*)ws;
  unsigned short* W2b = (unsigned short*)(ws + 1376256);
  unsigned short* W3b = (unsigned short*)(ws + 1376256 + 131072);
  unsigned short* h   = (unsigned short*)(ws + 1638400);

  hipLaunchKernelGGL(prep_w1, dim3(2688), dim3(256), 0, stream, W_cls, W_box, W1, Wp);
  hipLaunchKernelGGL(prep_w23, dim3(512), dim3(256), 0, stream, W2, W3, W2b, W3b);
  hipLaunchKernelGGL(g1_kernel, dim3(6144), dim3(448), 0, stream,
                     x, Wp, b_cls, b_box, b1, scores, deltas, h);
  hipLaunchKernelGGL((g23_kernel<1, 1>), dim3(R_TOT / 128), dim3(512), 0, stream,
                     h, W2b, b2, (void*)h);       // in place: h1 -> h2 (block-local rows)
  hipLaunchKernelGGL((g23_kernel<0, 0>), dim3(R_TOT / 128), dim3(512), 0, stream,
                     h, W3b, b3, (void*)embeds);
}

// Round 14
// 462.102 us; speedup vs baseline: 1.4526x; 1.0507x over previous
//
#include <hip/hip_runtime.h>
#include <hip/hip_bf16.h>
#include <stdint.h>

#define R_TOT   131072
#define D_IN    1024
#define N_CLS   81
#define N_BOX   320
#define N_H     256
#define N1_USED 657
#define N1_PAD  672
#define NB_COLS 336   // per-block N (half of 672)

typedef __attribute__((ext_vector_type(8))) short short8;
typedef __attribute__((ext_vector_type(4))) float f32x4;

__device__ __forceinline__ unsigned short f2bf(float f) {
  union { float f; unsigned u; } v; v.f = f;
  unsigned r = v.u + 0x7FFFu + ((v.u >> 16) & 1u);
  return (unsigned short)(r >> 16);
}

__device__ __forceinline__ short8 cvt8(float4 a, float4 b) {
  short8 v;
  v[0] = (short)f2bf(a.x); v[1] = (short)f2bf(a.y);
  v[2] = (short)f2bf(a.z); v[3] = (short)f2bf(a.w);
  v[4] = (short)f2bf(b.x); v[5] = (short)f2bf(b.y);
  v[6] = (short)f2bf(b.z); v[7] = (short)f2bf(b.w);
  return v;
}

__device__ __forceinline__ void async_lds16(void* lds, const void* g) {
  __builtin_amdgcn_global_load_lds(
      (const __attribute__((address_space(1))) unsigned int*)g,
      (__attribute__((address_space(3))) unsigned int*)lds, 16, 0, 0);
}

// ---------------- prep: pack W_big into K-panels [32][672][32] bf16 (PLAIN) ----
// B is consumed by direct global->reg fragment loads now; no swizzle baked.
__global__ void prep_w1(const float* __restrict__ Wc, const float* __restrict__ Wb,
                        const float* __restrict__ W1, unsigned short* __restrict__ Wp)
{
  int idx = blockIdx.x * 256 + threadIdx.x;      // < 672*1024
  int p   = idx / (N1_PAD * 32);
  int rem = idx % (N1_PAD * 32);
  int n   = rem >> 5;
  int kk  = rem & 31;
  int k   = p * 32 + kk;
  float w = 0.f;
  if (n < N_CLS)               w = Wc[(size_t)n * D_IN + k];
  else if (n < N_CLS + N_BOX)  w = Wb[(size_t)(n - N_CLS) * D_IN + k];
  else if (n < N1_USED)        w = W1[(size_t)(n - (N_CLS + N_BOX)) * D_IN + k];
  Wp[idx] = f2bf(w);
}

__global__ void prep_w23(const float* __restrict__ W2, const float* __restrict__ W3,
                         unsigned short* __restrict__ W2b, unsigned short* __restrict__ W3b)
{
  int idx = blockIdx.x * 256 + threadIdx.x;      // < 131072
  if (idx < 65536) W2b[idx] = f2bf(W2[idx]);
  else             W3b[idx - 65536] = f2bf(W3[idx - 65536]);
}

// ---------------- GEMM1: 64(M) x 336(N) per block, K=1024 ----------------
// Grid 4096 = 2048 M-tiles x 2 N-panels; bijective XCD swizzle (x re-reads hit L2/L3).
// 448 threads (7 waves), wave wc owns cols [wc*48,+48), acc[4][3].
// B: NO LDS -- each wave loads its 3 B fragments per K-step DIRECTLY from Wp
//    (L2-resident, 1.4 MB) into registers, prefetched one step ahead. The
//    K-panel layout makes one global_load_dwordx4 per lane == one MFMA B-frag.
//    (LDS staging of B had zero cross-wave reuse -- pure overhead.)
// A: R9's reg-staged path (fp32 global -> cvt8 -> ds_write bf16), 8 KB dbuf,
//    XOR-swizzled slot^((row>>1)&3) on write AND read -> 2-way (free).
// Sync: raw s_barrier with lgkmcnt(0)-only wait -- vmem NEVER drains in-loop,
//    so A/B global prefetch stays in flight across steps.
__global__ __launch_bounds__(448) void g1_kernel(
    const float* __restrict__ x, const unsigned short* __restrict__ Wp,
    const float* __restrict__ b_cls, const float* __restrict__ b_box,
    const float* __restrict__ b1,
    float* __restrict__ scores, float* __restrict__ deltas,
    unsigned short* __restrict__ h1)
{
  __shared__ __attribute__((aligned(16))) unsigned short As[2][64 * 32];  // 8 KB total

  const int tid  = threadIdx.x;
  const int wave = tid >> 6;
  const int lane = tid & 63;
  // bijective XCD-chunk swizzle (nwg = 4096, 4096 % 8 == 0)
  const int orig  = blockIdx.x;
  const int work  = (orig & 7) * 512 + (orig >> 3);
  const int m0    = (work >> 1) * 64;
  const int nbase = (work & 1) * NB_COLS;

  const int arow = tid >> 2;          // A-staging row (tid < 256)
  const int akq  = tid & 3;           // A-staging 16B slot
  const int awoff = arow * 32 + ((akq ^ ((arow >> 1) & 3)) << 3);  // swizzled write

  const int lr = lane & 15;
  const int g2 = (lane >> 4) * 8;     // k-octet element offset

  f32x4 acc[4][3];
#pragma unroll
  for (int i = 0; i < 4; ++i)
#pragma unroll
    for (int j = 0; j < 3; ++j)
      acc[i][j] = (f32x4){0.f, 0.f, 0.f, 0.f};

  // per-lane B fragment pointer: col = nbase + wave*48 + lr, k-octet g2.
  // ni steps by 16 cols = 512 elements; k-step advances by 672*32 elements.
  const unsigned short* bptr = Wp + (size_t)(nbase + wave * 48 + lr) * 32 + g2;
  const size_t BSTEP = (size_t)N1_PAD * 32;

  // ---- prologue: A(0) -> As[0]; B(0) -> regs ----
  if (tid < 256) {
    const float* s = x + (size_t)(m0 + arow) * D_IN + akq * 8;
    float4 f0 = *(const float4*)s;
    float4 f1 = *(const float4*)(s + 4);
    *(short8*)&As[0][awoff] = cvt8(f0, f1);
  }
  short8 bCur0 = *(const short8*)(bptr);
  short8 bCur1 = *(const short8*)(bptr + 512);
  short8 bCur2 = *(const short8*)(bptr + 1024);
  bptr += BSTEP;
  asm volatile("s_waitcnt lgkmcnt(0)" ::: "memory");
  __builtin_amdgcn_sched_barrier(0);
  __builtin_amdgcn_s_barrier();

#pragma unroll 2
  for (int kp = 0; kp < 32; ++kp) {
    const int cur = kp & 1;

    // issue next-step prefetches first (land under this step's compute)
    float4 f0, f1;
    if (kp < 31 && tid < 256) {
      const float* s = x + (size_t)(m0 + arow) * D_IN + (size_t)(kp + 1) * 32 + akq * 8;
      f0 = *(const float4*)s;
      f1 = *(const float4*)(s + 4);
    }
    short8 bn0, bn1, bn2;
    if (kp < 31) {
      bn0 = *(const short8*)(bptr);
      bn1 = *(const short8*)(bptr + 512);
      bn2 = *(const short8*)(bptr + 1024);
      bptr += BSTEP;
    }

    // compute: per mi, swizzled A-frag read then its 3 MFMAs
#pragma unroll
    for (int mi = 0; mi < 4; ++mi) {
      const int r  = mi * 16 + lr;
      const int sl = (g2 >> 3) ^ ((r >> 1) & 3);
      short8 af = *(const short8*)&As[cur][r * 32 + (sl << 3)];
      acc[mi][0] = __builtin_amdgcn_mfma_f32_16x16x32_bf16(af, bCur0, acc[mi][0], 0, 0, 0);
      acc[mi][1] = __builtin_amdgcn_mfma_f32_16x16x32_bf16(af, bCur1, acc[mi][1], 0, 0, 0);
      acc[mi][2] = __builtin_amdgcn_mfma_f32_16x16x32_bf16(af, bCur2, acc[mi][2], 0, 0, 0);
    }

    if (kp < 31 && tid < 256)
      *(short8*)&As[cur ^ 1][awoff] = cvt8(f0, f1);   // waits its own vmem via reg dep

    if (kp < 31) { bCur0 = bn0; bCur1 = bn1; bCur2 = bn2; }

    // A-visibility only: drain LDS ops, keep vmem in flight, then barrier.
    asm volatile("s_waitcnt lgkmcnt(0)" ::: "memory");
    __builtin_amdgcn_sched_barrier(0);
    __builtin_amdgcn_s_barrier();
  }

  // ---- epilogue: split cols into scores / deltas / h1 ----
  const int rbase = m0 + ((lane >> 4) << 2);
#pragma unroll
  for (int mi = 0; mi < 4; ++mi) {
#pragma unroll
    for (int ni = 0; ni < 3; ++ni) {
      int n = nbase + wave * 48 + ni * 16 + lr;
      if (n >= N1_USED) continue;
      if (n < N_CLS) {
        float bb = b_cls[n];
#pragma unroll
        for (int j = 0; j < 4; ++j) {
          int r = rbase + mi * 16 + j;
          scores[(size_t)r * N_CLS + n] = acc[mi][ni][j] + bb;
        }
      } else if (n < N_CLS + N_BOX) {
        int nb = n - N_CLS;
        float bb = b_box[nb];
#pragma unroll
        for (int j = 0; j < 4; ++j) {
          int r = rbase + mi * 16 + j;
          deltas[(size_t)r * N_BOX + nb] = acc[mi][ni][j] + bb;
        }
      } else {
        int nh = n - (N_CLS + N_BOX);
        float bb = b1[nh];
#pragma unroll
        for (int j = 0; j < 4; ++j) {
          int r = rbase + mi * 16 + j;
          float h = acc[mi][ni][j] + bb;
          h1[(size_t)r * N_H + nh] = f2bf(fmaxf(h, 0.f));
        }
      }
    }
  }
}

// ---------------- GEMM2/3: full-row blocks, 128(M) x 256(N=all), K=256, BK=32 ----
// 512 threads (8 waves), wave (wm,wn) = (wave>>2, wave&3), per-wave 64x64 output.
// Each block reads ONLY A rows [m0,m0+128) and writes ONLY those rows ->
// in-place (out==A) is block-local and race-free. Grid is (R/128, 1).
__device__ __forceinline__ void g23_stage(unsigned short* Asb, unsigned short* Bsb,
    const unsigned short* __restrict__ A, const unsigned short* __restrict__ Bw,
    int m0, int kp, int tid)
{
  {
    int row = tid >> 2, kq = tid & 3;             // A: 512 chunks of 16B
    async_lds16((char*)Asb + tid * 16,
                (const char*)(A + (size_t)(m0 + row) * N_H + (size_t)kp * 32 + kq * 8));
  }
#pragma unroll
  for (int i = 0; i < 2; ++i) {                   // B: 1024 chunks of 16B
    int chunk = tid + i * 512;
    int row = chunk >> 2, kq = chunk & 3;
    async_lds16((char*)Bsb + chunk * 16,
                (const char*)(Bw + (size_t)row * N_H + (size_t)kp * 32 + kq * 8));
  }
}

template <int RELU, int OUT_BF16>
__global__ __launch_bounds__(512, 1) void g23_kernel(
    const unsigned short* __restrict__ A, const unsigned short* __restrict__ Bw,
    const float* __restrict__ bias, void* __restrict__ outv)
{
  __shared__ __attribute__((aligned(16))) unsigned short As[2][128 * 32];
  __shared__ __attribute__((aligned(16))) unsigned short Bs[2][256 * 32];
  const int tid  = threadIdx.x;
  const int wave = tid >> 6, lane = tid & 63;
  const int wm = wave >> 2, wn = wave & 3;
  const int m0 = blockIdx.x * 128;

  f32x4 acc[4][4];
#pragma unroll
  for (int i = 0; i < 4; ++i)
#pragma unroll
    for (int j = 0; j < 4; ++j)
      acc[i][j] = (f32x4){0.f, 0.f, 0.f, 0.f};

  g23_stage(&As[0][0], &Bs[0][0], A, Bw, m0, 0, tid);
  __syncthreads();

  const int lr = lane & 15;
  const int lk = (lane >> 4) * 8;

  for (int kp = 0; kp < 8; ++kp) {
    const int cur = kp & 1, nxt = cur ^ 1;
    if (kp < 7) g23_stage(&As[nxt][0], &Bs[nxt][0], A, Bw, m0, kp + 1, tid);

    short8 af[4], bfr[4];
#pragma unroll
    for (int mi = 0; mi < 4; ++mi)
      af[mi] = *(const short8*)&As[cur][(wm * 64 + mi * 16 + lr) * 32 + lk];
#pragma unroll
    for (int ni = 0; ni < 4; ++ni)
      bfr[ni] = *(const short8*)&Bs[cur][(wn * 64 + ni * 16 + lr) * 32 + lk];
#pragma unroll
    for (int mi = 0; mi < 4; ++mi)
#pragma unroll
      for (int ni = 0; ni < 4; ++ni)
        acc[mi][ni] = __builtin_amdgcn_mfma_f32_16x16x32_bf16(af[mi], bfr[ni], acc[mi][ni], 0, 0, 0);
    __syncthreads();
  }

  // All LDS reads of A done; safe to overwrite our own rows (even if out==A).
#pragma unroll
  for (int mi = 0; mi < 4; ++mi) {
#pragma unroll
    for (int ni = 0; ni < 4; ++ni) {
      int n = wn * 64 + ni * 16 + lr;
      float bb = bias[n];
#pragma unroll
      for (int j = 0; j < 4; ++j) {
        int r = m0 + wm * 64 + mi * 16 + ((lane >> 4) << 2) + j;
        float v = acc[mi][ni][j] + bb;
        if (RELU) v = fmaxf(v, 0.f);
        if (OUT_BF16) ((unsigned short*)outv)[(size_t)r * N_H + n] = f2bf(v);
        else          ((float*)outv)[(size_t)r * N_H + n] = v;
      }
    }
  }
}

// ---------------- launch ----------------
extern "C" void kernel_launch(void* const* d_in, const int* in_sizes, int n_in,
                              void* d_out, int out_size, void* d_ws, size_t ws_size,
                              hipStream_t stream)
{
  const float* x     = (const float*)d_in[0];
  const float* W_cls = (const float*)d_in[1];
  const float* b_cls = (const float*)d_in[2];
  const float* W_box = (const float*)d_in[3];
  const float* b_box = (const float*)d_in[4];
  const float* W1    = (const float*)d_in[5];
  const float* b1    = (const float*)d_in[6];
  const float* W2    = (const float*)d_in[7];
  const float* b2    = (const float*)d_in[8];
  const float* W3    = (const float*)d_in[9];
  const float* b3    = (const float*)d_in[10];

  float* scores = (float*)d_out;
  float* deltas = scores + (size_t)R_TOT * N_CLS;
  float* embeds = deltas + (size_t)R_TOT * N_BOX;

  // Scratch layout (total ~65.6 MB):
  //   Wp  : 672*1024 bf16      = 1,376,256 B   (plain K-panel layout)
  //   W2b :  65536 bf16        =   131,072 B
  //   W3b :  65536 bf16        =   131,072 B
  //   h   : 131072*256 bf16    = 67,108,864 B  (h1; GEMM2 overwrites in place -> h2)
  char* ws = (char*)d_ws;
  unsigned short* Wp  = (unsigned short*)ws;
  unsigned short* W2b = (unsigned short*)(ws + 1376256);
  unsigned short* W3b = (unsigned short*)(ws + 1376256 + 131072);
  unsigned short* h   = (unsigned short*)(ws + 1638400);

  hipLaunchKernelGGL(prep_w1, dim3(2688), dim3(256), 0, stream, W_cls, W_box, W1, Wp);
  hipLaunchKernelGGL(prep_w23, dim3(512), dim3(256), 0, stream, W2, W3, W2b, W3b);
  hipLaunchKernelGGL(g1_kernel, dim3(4096), dim3(448), 0, stream,
                     x, Wp, b_cls, b_box, b1, scores, deltas, h);
  hipLaunchKernelGGL((g23_kernel<1, 1>), dim3(R_TOT / 128), dim3(512), 0, stream,
                     h, W2b, b2, (void*)h);       // in place: h1 -> h2 (block-local rows)
  hipLaunchKernelGGL((g23_kernel<0, 0>), dim3(R_TOT / 128), dim3(512), 0, stream,
                     h, W3b, b3, (void*)embeds);
}

// Round 15
// 441.074 us; speedup vs baseline: 1.5218x; 1.0477x over previous
//
#include <hip/hip_runtime.h>
#include <hip/hip_bf16.h>
#include <stdint.h>

#define R_TOT   131072
#define D_IN    1024
#define N_CLS   81
#define N_BOX   320
#define N_H     256
#define N1_USED 657
#define N1_PAD  672
#define NB_COLS 336   // per-block N (half of 672)

typedef __attribute__((ext_vector_type(8))) short short8;
typedef __attribute__((ext_vector_type(4))) float f32x4;

__device__ __forceinline__ unsigned short f2bf(float f) {
  union { float f; unsigned u; } v; v.f = f;
  unsigned r = v.u + 0x7FFFu + ((v.u >> 16) & 1u);
  return (unsigned short)(r >> 16);
}

__device__ __forceinline__ short8 cvt8(float4 a, float4 b) {
  short8 v;
  v[0] = (short)f2bf(a.x); v[1] = (short)f2bf(a.y);
  v[2] = (short)f2bf(a.z); v[3] = (short)f2bf(a.w);
  v[4] = (short)f2bf(b.x); v[5] = (short)f2bf(b.y);
  v[6] = (short)f2bf(b.z); v[7] = (short)f2bf(b.w);
  return v;
}

__device__ __forceinline__ void async_lds16(void* lds, const void* g) {
  __builtin_amdgcn_global_load_lds(
      (const __attribute__((address_space(1))) unsigned int*)g,
      (__attribute__((address_space(3))) unsigned int*)lds, 16, 0, 0);
}

// ---------------- prep: pack W_big into K-panels [32][672][32] bf16 (PLAIN) ----
__global__ void prep_w1(const float* __restrict__ Wc, const float* __restrict__ Wb,
                        const float* __restrict__ W1, unsigned short* __restrict__ Wp)
{
  int idx = blockIdx.x * 256 + threadIdx.x;      // < 672*1024
  int p   = idx / (N1_PAD * 32);
  int rem = idx % (N1_PAD * 32);
  int n   = rem >> 5;
  int kk  = rem & 31;
  int k   = p * 32 + kk;
  float w = 0.f;
  if (n < N_CLS)               w = Wc[(size_t)n * D_IN + k];
  else if (n < N_CLS + N_BOX)  w = Wb[(size_t)(n - N_CLS) * D_IN + k];
  else if (n < N1_USED)        w = W1[(size_t)(n - (N_CLS + N_BOX)) * D_IN + k];
  Wp[idx] = f2bf(w);
}

__global__ void prep_w23(const float* __restrict__ W2, const float* __restrict__ W3,
                         unsigned short* __restrict__ W2b, unsigned short* __restrict__ W3b)
{
  int idx = blockIdx.x * 256 + threadIdx.x;      // < 131072
  if (idx < 65536) W2b[idx] = f2bf(W2[idx]);
  else             W3b[idx - 65536] = f2bf(W3[idx - 65536]);
}

// ---------------- GEMM1: 64(M) x 336(N) per block, K=1024 ----------------
// Grid 4096 = 2048 M-tiles x 2 N-panels; bijective XCD swizzle (x re-reads hit L2/L3).
// 448 threads (7 waves), wave wc owns cols [wc*48,+48), acc[4][3].
// B: direct global->reg from L2-resident Wp, prefetched one step ahead (R14).
// A: staged in TWO 64 KB bf16 chunks [64 rows][512 k], XOR-swizzled slot^(row&7).
//    Only 4 barriers per block (2 per chunk) -- the 16-step inner run has NO
//    barriers, no ds_writes, no cvts: {3 B-loads + 4 ds_read + 12 MFMA}/wave-step,
//    freely pipelined by the compiler. fp32->bf16 cvt happens once per chunk in
//    the staging prologue (reg-staged, unroll 3 bounds transient pressure).
// LDS 64 KB + VGPR<=128 (launch_bounds 448,4) -> 2 blocks/CU: one block's
// staging overlaps the other's compute.
__global__ __launch_bounds__(448, 4) void g1_kernel(
    const float* __restrict__ x, const unsigned short* __restrict__ Wp,
    const float* __restrict__ b_cls, const float* __restrict__ b_box,
    const float* __restrict__ b1,
    float* __restrict__ scores, float* __restrict__ deltas,
    unsigned short* __restrict__ h1)
{
  __shared__ __attribute__((aligned(16))) unsigned short As[64 * 512];  // 64 KB

  const int tid  = threadIdx.x;
  const int wave = tid >> 6;
  const int lane = tid & 63;
  // bijective XCD-chunk swizzle (nwg = 4096, 4096 % 8 == 0)
  const int orig  = blockIdx.x;
  const int work  = (orig & 7) * 512 + (orig >> 3);
  const int m0    = (work >> 1) * 64;
  const int nbase = (work & 1) * NB_COLS;

  const int lr  = lane & 15;
  const int hig = lane >> 4;          // 0..3
  const int g2  = hig * 8;            // k-octet element offset

  f32x4 acc[4][3];
#pragma unroll
  for (int i = 0; i < 4; ++i)
#pragma unroll
    for (int j = 0; j < 3; ++j)
      acc[i][j] = (f32x4){0.f, 0.f, 0.f, 0.f};

  // per-lane B fragment pointer: col = nbase + wave*48 + lr, k-octet g2.
  const unsigned short* bptr = Wp + (size_t)(nbase + wave * 48 + lr) * 32 + g2;
  const size_t BSTEP = (size_t)N1_PAD * 32;

  short8 bCur0 = *(const short8*)(bptr);
  short8 bCur1 = *(const short8*)(bptr + 512);
  short8 bCur2 = *(const short8*)(bptr + 1024);
  bptr += BSTEP;

#pragma unroll 2
  for (int kp = 0; kp < 32; ++kp) {
    // ---- chunk staging every 16 steps: A[64][512] bf16, swizzled ----
    if ((kp & 15) == 0) {
      const int c0 = (kp >> 4) * 512;              // chunk k-base
      if (kp) __syncthreads();                     // all reads of prev chunk done
#pragma unroll 3
      for (int i = 0; i < 9; ++i) {                // 9*448 = 4032 slots
        int idx = tid + i * 448;
        int row = idx >> 6, s = idx & 63;
        const float* src = x + (size_t)(m0 + row) * D_IN + c0 + s * 8;
        float4 f0 = *(const float4*)src;
        float4 f1 = *(const float4*)(src + 4);
        *(short8*)&As[row * 512 + ((s ^ (row & 7)) << 3)] = cvt8(f0, f1);
      }
      if (tid < 64) {                              // tail: row 63
        int s = tid;
        const float* src = x + (size_t)(m0 + 63) * D_IN + c0 + s * 8;
        float4 f0 = *(const float4*)src;
        float4 f1 = *(const float4*)(src + 4);
        *(short8*)&As[63 * 512 + ((s ^ 7) << 3)] = cvt8(f0, f1);
      }
      __syncthreads();
    }

    // ---- B prefetch for next step (stays in flight across everything) ----
    short8 bn0, bn1, bn2;
    if (kp < 31) {
      bn0 = *(const short8*)(bptr);
      bn1 = *(const short8*)(bptr + 512);
      bn2 = *(const short8*)(bptr + 1024);
      bptr += BSTEP;
    }

    // ---- compute: per mi, swizzled A-frag read then its 3 MFMAs ----
    const int kk = kp & 15;
    const int sb = kk * 4 + hig;                   // base slot for this lane
#pragma unroll
    for (int mi = 0; mi < 4; ++mi) {
      const int r  = mi * 16 + lr;
      const int sl = sb ^ (r & 7);
      short8 af = *(const short8*)&As[r * 512 + (sl << 3)];
      acc[mi][0] = __builtin_amdgcn_mfma_f32_16x16x32_bf16(af, bCur0, acc[mi][0], 0, 0, 0);
      acc[mi][1] = __builtin_amdgcn_mfma_f32_16x16x32_bf16(af, bCur1, acc[mi][1], 0, 0, 0);
      acc[mi][2] = __builtin_amdgcn_mfma_f32_16x16x32_bf16(af, bCur2, acc[mi][2], 0, 0, 0);
    }

    if (kp < 31) { bCur0 = bn0; bCur1 = bn1; bCur2 = bn2; }
  }

  // ---- epilogue: split cols into scores / deltas / h1 ----
  const int rbase = m0 + (hig << 2);
#pragma unroll
  for (int mi = 0; mi < 4; ++mi) {
#pragma unroll
    for (int ni = 0; ni < 3; ++ni) {
      int n = nbase + wave * 48 + ni * 16 + lr;
      if (n >= N1_USED) continue;
      if (n < N_CLS) {
        float bb = b_cls[n];
#pragma unroll
        for (int j = 0; j < 4; ++j) {
          int r = rbase + mi * 16 + j;
          scores[(size_t)r * N_CLS + n] = acc[mi][ni][j] + bb;
        }
      } else if (n < N_CLS + N_BOX) {
        int nb = n - N_CLS;
        float bb = b_box[nb];
#pragma unroll
        for (int j = 0; j < 4; ++j) {
          int r = rbase + mi * 16 + j;
          deltas[(size_t)r * N_BOX + nb] = acc[mi][ni][j] + bb;
        }
      } else {
        int nh = n - (N_CLS + N_BOX);
        float bb = b1[nh];
#pragma unroll
        for (int j = 0; j < 4; ++j) {
          int r = rbase + mi * 16 + j;
          float h = acc[mi][ni][j] + bb;
          h1[(size_t)r * N_H + nh] = f2bf(fmaxf(h, 0.f));
        }
      }
    }
  }
}

// ---------------- GEMM2/3: full-row blocks, 128(M) x 256(N=all), K=256, BK=32 ----
// 512 threads (8 waves), wave (wm,wn) = (wave>>2, wave&3), per-wave 64x64 output.
// Each block reads ONLY A rows [m0,m0+128) and writes ONLY those rows ->
// in-place (out==A) is block-local and race-free. Grid is (R/128, 1).
__device__ __forceinline__ void g23_stage(unsigned short* Asb, unsigned short* Bsb,
    const unsigned short* __restrict__ A, const unsigned short* __restrict__ Bw,
    int m0, int kp, int tid)
{
  {
    int row = tid >> 2, kq = tid & 3;             // A: 512 chunks of 16B
    async_lds16((char*)Asb + tid * 16,
                (const char*)(A + (size_t)(m0 + row) * N_H + (size_t)kp * 32 + kq * 8));
  }
#pragma unroll
  for (int i = 0; i < 2; ++i) {                   // B: 1024 chunks of 16B
    int chunk = tid + i * 512;
    int row = chunk >> 2, kq = chunk & 3;
    async_lds16((char*)Bsb + chunk * 16,
                (const char*)(Bw + (size_t)row * N_H + (size_t)kp * 32 + kq * 8));
  }
}

template <int RELU, int OUT_BF16>
__global__ __launch_bounds__(512, 1) void g23_kernel(
    const unsigned short* __restrict__ A, const unsigned short* __restrict__ Bw,
    const float* __restrict__ bias, void* __restrict__ outv)
{
  __shared__ __attribute__((aligned(16))) unsigned short As[2][128 * 32];
  __shared__ __attribute__((aligned(16))) unsigned short Bs[2][256 * 32];
  const int tid  = threadIdx.x;
  const int wave = tid >> 6, lane = tid & 63;
  const int wm = wave >> 2, wn = wave & 3;
  const int m0 = blockIdx.x * 128;

  f32x4 acc[4][4];
#pragma unroll
  for (int i = 0; i < 4; ++i)
#pragma unroll
    for (int j = 0; j < 4; ++j)
      acc[i][j] = (f32x4){0.f, 0.f, 0.f, 0.f};

  g23_stage(&As[0][0], &Bs[0][0], A, Bw, m0, 0, tid);
  __syncthreads();

  const int lr = lane & 15;
  const int lk = (lane >> 4) * 8;

  for (int kp = 0; kp < 8; ++kp) {
    const int cur = kp & 1, nxt = cur ^ 1;
    if (kp < 7) g23_stage(&As[nxt][0], &Bs[nxt][0], A, Bw, m0, kp + 1, tid);

    short8 af[4], bfr[4];
#pragma unroll
    for (int mi = 0; mi < 4; ++mi)
      af[mi] = *(const short8*)&As[cur][(wm * 64 + mi * 16 + lr) * 32 + lk];
#pragma unroll
    for (int ni = 0; ni < 4; ++ni)
      bfr[ni] = *(const short8*)&Bs[cur][(wn * 64 + ni * 16 + lr) * 32 + lk];
#pragma unroll
    for (int mi = 0; mi < 4; ++mi)
#pragma unroll
      for (int ni = 0; ni < 4; ++ni)
        acc[mi][ni] = __builtin_amdgcn_mfma_f32_16x16x32_bf16(af[mi], bfr[ni], acc[mi][ni], 0, 0, 0);
    __syncthreads();
  }

  // All LDS reads of A done; safe to overwrite our own rows (even if out==A).
#pragma unroll
  for (int mi = 0; mi < 4; ++mi) {
#pragma unroll
    for (int ni = 0; ni < 4; ++ni) {
      int n = wn * 64 + ni * 16 + lr;
      float bb = bias[n];
#pragma unroll
      for (int j = 0; j < 4; ++j) {
        int r = m0 + wm * 64 + mi * 16 + ((lane >> 4) << 2) + j;
        float v = acc[mi][ni][j] + bb;
        if (RELU) v = fmaxf(v, 0.f);
        if (OUT_BF16) ((unsigned short*)outv)[(size_t)r * N_H + n] = f2bf(v);
        else          ((float*)outv)[(size_t)r * N_H + n] = v;
      }
    }
  }
}

// ---------------- launch ----------------
extern "C" void kernel_launch(void* const* d_in, const int* in_sizes, int n_in,
                              void* d_out, int out_size, void* d_ws, size_t ws_size,
                              hipStream_t stream)
{
  const float* x     = (const float*)d_in[0];
  const float* W_cls = (const float*)d_in[1];
  const float* b_cls = (const float*)d_in[2];
  const float* W_box = (const float*)d_in[3];
  const float* b_box = (const float*)d_in[4];
  const float* W1    = (const float*)d_in[5];
  const float* b1    = (const float*)d_in[6];
  const float* W2    = (const float*)d_in[7];
  const float* b2    = (const float*)d_in[8];
  const float* W3    = (const float*)d_in[9];
  const float* b3    = (const float*)d_in[10];

  float* scores = (float*)d_out;
  float* deltas = scores + (size_t)R_TOT * N_CLS;
  float* embeds = deltas + (size_t)R_TOT * N_BOX;

  // Scratch layout (total ~65.6 MB):
  //   Wp  : 672*1024 bf16      = 1,376,256 B   (plain K-panel layout)
  //   W2b :  65536 bf16        =   131,072 B
  //   W3b :  65536 bf16        =   131,072 B
  //   h   : 131072*256 bf16    = 67,108,864 B  (h1; GEMM2 overwrites in place -> h2)
  char* ws = (char*)d_ws;
  unsigned short* Wp  = (unsigned short*)ws;
  unsigned short* W2b = (unsigned short*)(ws + 1376256);
  unsigned short* W3b = (unsigned short*)(ws + 1376256 + 131072);
  unsigned short* h   = (unsigned short*)(ws + 1638400);

  hipLaunchKernelGGL(prep_w1, dim3(2688), dim3(256), 0, stream, W_cls, W_box, W1, Wp);
  hipLaunchKernelGGL(prep_w23, dim3(512), dim3(256), 0, stream, W2, W3, W2b, W3b);
  hipLaunchKernelGGL(g1_kernel, dim3(4096), dim3(448), 0, stream,
                     x, Wp, b_cls, b_box, b1, scores, deltas, h);
  hipLaunchKernelGGL((g23_kernel<1, 1>), dim3(R_TOT / 128), dim3(512), 0, stream,
                     h, W2b, b2, (void*)h);       // in place: h1 -> h2 (block-local rows)
  hipLaunchKernelGGL((g23_kernel<0, 0>), dim3(R_TOT / 128), dim3(512), 0, stream,
                     h, W3b, b3, (void*)embeds);
}